// Round 1
// baseline (1253.688 us; speedup 1.0000x reference)
//
#include <hip/hip_runtime.h>

#define Bb 8
#define Nn 1024
#define Cc 768
#define Hh 12
#define Dd 64
#define BHn (Bb*Hh)   // 96
#define Mm (Bb*Nn)    // 8192
#define TCc (3*Cc)    // 2304

// fragment row/col offsets: t*4+{0..3} and 64+t*4+{0..3}
__device__ __forceinline__ int frag_idx(int t, int r) {
    return (r < 4) ? (t*4 + r) : (64 + t*4 + (r - 4));
}

// ---------------------------------------------------------------------------
// Kernel 1: QKV projection.  q/k/v[b,h,n,d] = sum_c x[b,n,c] * w_qkv[t*768+h*64+d, c]
// NT GEMM: A = x [8192 x 768] row-major, B = w_qkv [2304 x 768] row-major.
// 128x128 tile, BK=16, 256 threads, 8x8 per thread.
// ---------------------------------------------------------------------------
__global__ __launch_bounds__(256)
void qkv_kernel(const float* __restrict__ x, const float* __restrict__ w,
                float* __restrict__ Q, float* __restrict__ K, float* __restrict__ V)
{
    __shared__ float As[16][132];
    __shared__ float Bs[16][132];
    const int tid = threadIdx.x;
    const int tx = tid & 15, ty = tid >> 4;
    const int m0 = blockIdx.x * 128;
    const int j0 = blockIdx.y * 128;

    float acc[8][8];
#pragma unroll
    for (int i = 0; i < 8; ++i)
#pragma unroll
        for (int j = 0; j < 8; ++j) acc[i][j] = 0.f;

    for (int k0 = 0; k0 < Cc; k0 += 16) {
#pragma unroll
        for (int t = 0; t < 2; ++t) {
            int idx = tid + t * 256;
            int row = idx >> 2, c4 = idx & 3;
            float4 a = *reinterpret_cast<const float4*>(x + (size_t)(m0 + row) * Cc + k0 + c4 * 4);
            As[c4*4+0][row] = a.x; As[c4*4+1][row] = a.y;
            As[c4*4+2][row] = a.z; As[c4*4+3][row] = a.w;
            float4 b = *reinterpret_cast<const float4*>(w + (size_t)(j0 + row) * Cc + k0 + c4 * 4);
            Bs[c4*4+0][row] = b.x; Bs[c4*4+1][row] = b.y;
            Bs[c4*4+2][row] = b.z; Bs[c4*4+3][row] = b.w;
        }
        __syncthreads();
#pragma unroll
        for (int k = 0; k < 16; ++k) {
            alignas(16) float a[8], b[8];
            *reinterpret_cast<float4*>(&a[0]) = *reinterpret_cast<const float4*>(&As[k][ty*4]);
            *reinterpret_cast<float4*>(&a[4]) = *reinterpret_cast<const float4*>(&As[k][64+ty*4]);
            *reinterpret_cast<float4*>(&b[0]) = *reinterpret_cast<const float4*>(&Bs[k][tx*4]);
            *reinterpret_cast<float4*>(&b[4]) = *reinterpret_cast<const float4*>(&Bs[k][64+tx*4]);
#pragma unroll
            for (int i = 0; i < 8; ++i)
#pragma unroll
                for (int j = 0; j < 8; ++j) acc[i][j] += a[i] * b[j];
        }
        __syncthreads();
    }

    // scatter epilogue: j = t*768 + h*64 + d  ->  {Q,K,V}[((b*H+h)*N+n)*D + d]
    const int t3  = j0 / Cc;               // 0,1,2 — tile never crosses (768 % 128 == 0)
    float* dst = (t3 == 0) ? Q : ((t3 == 1) ? K : V);
    const int jr0 = j0 - t3 * Cc;          // multiple of 128 in [0,768)
    const int h1  = jr0 >> 6;              // even; second col-fragment is h1+1
    const int d0  = tx * 4;
#pragma unroll
    for (int ri = 0; ri < 8; ++ri) {
        int row = frag_idx(ty, ri);
        int m = m0 + row;
        int b = m >> 10, n = m & 1023;
        float4 v0 = make_float4(acc[ri][0], acc[ri][1], acc[ri][2], acc[ri][3]);
        float4 v1 = make_float4(acc[ri][4], acc[ri][5], acc[ri][6], acc[ri][7]);
        *reinterpret_cast<float4*>(dst + ((size_t)((b*Hh + h1  ) * Nn + n)) * Dd + d0) = v0;
        *reinterpret_cast<float4*>(dst + ((size_t)((b*Hh + h1+1) * Nn + n)) * Dd + d0) = v1;
    }
}

// ---------------------------------------------------------------------------
// Kernel 2: scores. E[bh,i,j] = exp(scale * q_i . k_j), unnormalized, plus
// per-row sums accumulated atomically into rowsum[bh*N + i].
// No max-subtraction needed: scaled scores are ~N(0,1), exp can't overflow.
// ---------------------------------------------------------------------------
__global__ __launch_bounds__(256)
void scores_kernel(const float* __restrict__ Q, const float* __restrict__ Km,
                   float* __restrict__ E, float* __restrict__ rowsum)
{
    __shared__ float As[16][132];
    __shared__ float Bs[16][132];
    __shared__ float rs[128][17];
    const int tid = threadIdx.x;
    const int tx = tid & 15, ty = tid >> 4;
    const int bh = blockIdx.z;
    const int i0 = blockIdx.x * 128;
    const int j0 = blockIdx.y * 128;
    const float* Qb = Q  + (size_t)bh * Nn * Dd;
    const float* Kb = Km + (size_t)bh * Nn * Dd;
    float*       Eb = E  + (size_t)bh * Nn * Nn;

    float acc[8][8];
#pragma unroll
    for (int i = 0; i < 8; ++i)
#pragma unroll
        for (int j = 0; j < 8; ++j) acc[i][j] = 0.f;

    for (int k0 = 0; k0 < Dd; k0 += 16) {
#pragma unroll
        for (int t = 0; t < 2; ++t) {
            int idx = tid + t * 256;
            int row = idx >> 2, c4 = idx & 3;
            float4 a = *reinterpret_cast<const float4*>(Qb + (size_t)(i0 + row) * Dd + k0 + c4 * 4);
            As[c4*4+0][row] = a.x; As[c4*4+1][row] = a.y;
            As[c4*4+2][row] = a.z; As[c4*4+3][row] = a.w;
            float4 b = *reinterpret_cast<const float4*>(Kb + (size_t)(j0 + row) * Dd + k0 + c4 * 4);
            Bs[c4*4+0][row] = b.x; Bs[c4*4+1][row] = b.y;
            Bs[c4*4+2][row] = b.z; Bs[c4*4+3][row] = b.w;
        }
        __syncthreads();
#pragma unroll
        for (int k = 0; k < 16; ++k) {
            alignas(16) float a[8], b[8];
            *reinterpret_cast<float4*>(&a[0]) = *reinterpret_cast<const float4*>(&As[k][ty*4]);
            *reinterpret_cast<float4*>(&a[4]) = *reinterpret_cast<const float4*>(&As[k][64+ty*4]);
            *reinterpret_cast<float4*>(&b[0]) = *reinterpret_cast<const float4*>(&Bs[k][tx*4]);
            *reinterpret_cast<float4*>(&b[4]) = *reinterpret_cast<const float4*>(&Bs[k][64+tx*4]);
#pragma unroll
            for (int i = 0; i < 8; ++i)
#pragma unroll
                for (int j = 0; j < 8; ++j) acc[i][j] += a[i] * b[j];
        }
        __syncthreads();
    }

    const float scale = 0.125f;  // D^-0.5 = 64^-0.5
#pragma unroll
    for (int i = 0; i < 8; ++i)
#pragma unroll
        for (int j = 0; j < 8; ++j) acc[i][j] = __expf(acc[i][j] * scale);

#pragma unroll
    for (int ri = 0; ri < 8; ++ri) {
        int row = frag_idx(ty, ri);
        float4 e0 = make_float4(acc[ri][0], acc[ri][1], acc[ri][2], acc[ri][3]);
        float4 e1 = make_float4(acc[ri][4], acc[ri][5], acc[ri][6], acc[ri][7]);
        size_t base = (size_t)(i0 + row) * Nn + j0;
        *reinterpret_cast<float4*>(Eb + base + tx*4)      = e0;
        *reinterpret_cast<float4*>(Eb + base + 64 + tx*4) = e1;
        rs[row][tx] = e0.x + e0.y + e0.z + e0.w + e1.x + e1.y + e1.z + e1.w;
    }
    __syncthreads();
    if (tid < 128) {
        float s = 0.f;
#pragma unroll
        for (int t = 0; t < 16; ++t) s += rs[tid][t];
        atomicAdd(&rowsum[bh * Nn + i0 + tid], s);
    }
}

// ---------------------------------------------------------------------------
// Kernel 3: in-place softmax normalization of E (writes final attn output)
// fused with PV GEMM: O[b,n,h*64+d] = sum_j (E[bh,i,j]/rowsum) * V[bh,j,d].
// Each block owns rows [i0,i0+128) of one (b,h) — exclusive read+write.
// ---------------------------------------------------------------------------
__global__ __launch_bounds__(256)
void pv_kernel(float* __restrict__ E, const float* __restrict__ V,
               const float* __restrict__ rowsum, float* __restrict__ O)
{
    __shared__ float Ps[32][132];
    __shared__ float Vs[32][68];
    __shared__ float inv_s[128];
    const int tid = threadIdx.x;
    const int tx = tid & 15, ty = tid >> 4;
    const int i0 = blockIdx.x * 128;
    const int bh = blockIdx.y;
    float*       Eb = E + (size_t)bh * Nn * Nn;
    const float* Vb = V + (size_t)bh * Nn * Dd;

    if (tid < 128) inv_s[tid] = 1.0f / rowsum[bh * Nn + i0 + tid];
    __syncthreads();

    float acc[8][4];
#pragma unroll
    for (int i = 0; i < 8; ++i)
#pragma unroll
        for (int j = 0; j < 4; ++j) acc[i][j] = 0.f;

    for (int j0 = 0; j0 < Nn; j0 += 32) {
#pragma unroll
        for (int t = 0; t < 4; ++t) {           // E tile 128x32 = 1024 float4
            int idx = tid + t * 256;
            int row = idx >> 3, c4 = idx & 7;
            float* gp = Eb + (size_t)(i0 + row) * Nn + j0 + c4 * 4;
            float4 e = *reinterpret_cast<const float4*>(gp);
            float is = inv_s[row];
            float4 p = make_float4(e.x*is, e.y*is, e.z*is, e.w*is);
            *reinterpret_cast<float4*>(gp) = p;  // final attn value
            Ps[c4*4+0][row] = p.x; Ps[c4*4+1][row] = p.y;
            Ps[c4*4+2][row] = p.z; Ps[c4*4+3][row] = p.w;
        }
#pragma unroll
        for (int t = 0; t < 2; ++t) {           // V tile 32x64 = 512 float4
            int idx = tid + t * 256;
            int row = idx >> 4, c4 = idx & 15;
            float4 v = *reinterpret_cast<const float4*>(Vb + (size_t)(j0 + row) * Dd + c4 * 4);
            *reinterpret_cast<float4*>(&Vs[row][c4*4]) = v;
        }
        __syncthreads();
#pragma unroll
        for (int k = 0; k < 32; ++k) {
            alignas(16) float a[8];
            *reinterpret_cast<float4*>(&a[0]) = *reinterpret_cast<const float4*>(&Ps[k][ty*4]);
            *reinterpret_cast<float4*>(&a[4]) = *reinterpret_cast<const float4*>(&Ps[k][64+ty*4]);
            float4 b = *reinterpret_cast<const float4*>(&Vs[k][tx*4]);
#pragma unroll
            for (int i = 0; i < 8; ++i) {
                acc[i][0] += a[i] * b.x; acc[i][1] += a[i] * b.y;
                acc[i][2] += a[i] * b.z; acc[i][3] += a[i] * b.w;
            }
        }
        __syncthreads();
    }

    const int b = bh / Hh, h = bh % Hh;
#pragma unroll
    for (int ri = 0; ri < 8; ++ri) {
        int row = frag_idx(ty, ri);
        int n = i0 + row;
        float4 o = make_float4(acc[ri][0], acc[ri][1], acc[ri][2], acc[ri][3]);
        *reinterpret_cast<float4*>(O + ((size_t)(b * Nn + n)) * Cc + h * Dd + tx * 4) = o;
    }
}

// ---------------------------------------------------------------------------
// Kernel 4: output projection. out = O @ w_proj^T + b_proj, row-major direct.
// ---------------------------------------------------------------------------
__global__ __launch_bounds__(256)
void proj_kernel(const float* __restrict__ O, const float* __restrict__ w,
                 const float* __restrict__ bias, float* __restrict__ out)
{
    __shared__ float As[16][132];
    __shared__ float Bs[16][132];
    const int tid = threadIdx.x;
    const int tx = tid & 15, ty = tid >> 4;
    const int m0 = blockIdx.x * 128;
    const int j0 = blockIdx.y * 128;

    float acc[8][8];
#pragma unroll
    for (int i = 0; i < 8; ++i)
#pragma unroll
        for (int j = 0; j < 8; ++j) acc[i][j] = 0.f;

    for (int k0 = 0; k0 < Cc; k0 += 16) {
#pragma unroll
        for (int t = 0; t < 2; ++t) {
            int idx = tid + t * 256;
            int row = idx >> 2, c4 = idx & 3;
            float4 a = *reinterpret_cast<const float4*>(O + (size_t)(m0 + row) * Cc + k0 + c4 * 4);
            As[c4*4+0][row] = a.x; As[c4*4+1][row] = a.y;
            As[c4*4+2][row] = a.z; As[c4*4+3][row] = a.w;
            float4 b = *reinterpret_cast<const float4*>(w + (size_t)(j0 + row) * Cc + k0 + c4 * 4);
            Bs[c4*4+0][row] = b.x; Bs[c4*4+1][row] = b.y;
            Bs[c4*4+2][row] = b.z; Bs[c4*4+3][row] = b.w;
        }
        __syncthreads();
#pragma unroll
        for (int k = 0; k < 16; ++k) {
            alignas(16) float a[8], b[8];
            *reinterpret_cast<float4*>(&a[0]) = *reinterpret_cast<const float4*>(&As[k][ty*4]);
            *reinterpret_cast<float4*>(&a[4]) = *reinterpret_cast<const float4*>(&As[k][64+ty*4]);
            *reinterpret_cast<float4*>(&b[0]) = *reinterpret_cast<const float4*>(&Bs[k][tx*4]);
            *reinterpret_cast<float4*>(&b[4]) = *reinterpret_cast<const float4*>(&Bs[k][64+tx*4]);
#pragma unroll
            for (int i = 0; i < 8; ++i)
#pragma unroll
                for (int j = 0; j < 8; ++j) acc[i][j] += a[i] * b[j];
        }
        __syncthreads();
    }

    alignas(16) float bj[8];
#pragma unroll
    for (int c = 0; c < 8; ++c) bj[c] = bias[j0 + frag_idx(tx, c)];

#pragma unroll
    for (int ri = 0; ri < 8; ++ri) {
        int row = frag_idx(ty, ri);
        size_t m = (size_t)(m0 + row);
        float4 v0 = make_float4(acc[ri][0] + bj[0], acc[ri][1] + bj[1],
                                acc[ri][2] + bj[2], acc[ri][3] + bj[3]);
        float4 v1 = make_float4(acc[ri][4] + bj[4], acc[ri][5] + bj[5],
                                acc[ri][6] + bj[6], acc[ri][7] + bj[7]);
        *reinterpret_cast<float4*>(out + m * Cc + j0 + tx*4)      = v0;
        *reinterpret_cast<float4*>(out + m * Cc + j0 + 64 + tx*4) = v1;
    }
}

extern "C" void kernel_launch(void* const* d_in, const int* in_sizes, int n_in,
                              void* d_out, int out_size, void* d_ws, size_t ws_size,
                              hipStream_t stream)
{
    const float* x      = (const float*)d_in[0];
    const float* w_qkv  = (const float*)d_in[1];
    const float* w_proj = (const float*)d_in[2];
    const float* b_proj = (const float*)d_in[3];

    float* out  = (float*)d_out;                    // [8192 x 768]
    float* attn = out + (size_t)Mm * Cc;            // [96 x 1024 x 1024]

    const size_t qkv_elems = (size_t)BHn * Nn * Dd; // 6291456
    float* Q      = (float*)d_ws;
    float* K      = Q + qkv_elems;
    float* V      = K + qkv_elems;
    float* O      = V + qkv_elems;                  // [8192 x 768] attn@v result
    float* rowsum = O + (size_t)Mm * Cc;            // [96 x 1024]

    hipMemsetAsync(rowsum, 0, (size_t)BHn * Nn * sizeof(float), stream);

    qkv_kernel  <<<dim3(Mm/128, TCc/128), 256, 0, stream>>>(x, w_qkv, Q, K, V);
    scores_kernel<<<dim3(Nn/128, Nn/128, BHn), 256, 0, stream>>>(Q, K, attn, rowsum);
    pv_kernel   <<<dim3(Nn/128, BHn), 256, 0, stream>>>(attn, V, rowsum, O);
    proj_kernel <<<dim3(Mm/128, Cc/128), 256, 0, stream>>>(O, w_proj, b_proj, out);
}